// Round 6
// baseline (1605.316 us; speedup 1.0000x reference)
//
#include <hip/hip_runtime.h>
#include <math.h>

#define B_ 4
#define J_ 6890
#define D_ 256
#define L_ 4
#define H_ 8
#define DH_ 64
#define INNER_ 512
#define N_ 2048
#define FF_ 1024
#define M_ 13780
#define MP_ 13824   // M padded to multiple of 128

typedef float4 f4;
typedef __attribute__((ext_vector_type(8))) short s16x8;   // 8 bf16 (4 VGPRs)
typedef __attribute__((ext_vector_type(4))) float fx4;     // MFMA C/D

__device__ __forceinline__ float b2f(short s) {
    return __uint_as_float(((unsigned int)(unsigned short)s) << 16);
}
__device__ __forceinline__ short f2bf(float f) {   // RNE
    unsigned int u = __float_as_uint(f);
    unsigned int r = (u + 0x7FFFu + ((u >> 16) & 1u)) >> 16;
    return (short)r;
}
__device__ __forceinline__ float gelu_f(float v) {
    return 0.5f * v * (1.0f + erff(v * 0.70710678118654752440f));
}

// async global->LDS, 16B/lane. LDS dest: wave-uniform base + lane*16 (m97).
__device__ __forceinline__ void gld16(void* lds, const void* g) {
    __builtin_amdgcn_global_load_lds(
        (const __attribute__((address_space(1))) void*)g,
        (__attribute__((address_space(3))) void*)lds, 16, 0, 0);
}

// ---------------------------------------------------------------------------
// Fused token-embed + 1x1 conv (J->N) + pos-emb + pre-LN.  (fp32)
// ---------------------------------------------------------------------------
__global__ __launch_bounds__(256) void embed_ln_kernel(
    const float* __restrict__ x, const float* __restrict__ emb_w,
    const float* __restrict__ emb_b, const float* __restrict__ conv_w,
    const float* __restrict__ conv_b, const float* __restrict__ pos_emb,
    const float* __restrict__ g, const float* __restrict__ beta,
    float* __restrict__ hout)
{
    const int n = blockIdx.x, b = blockIdx.y, t = threadIdx.x;
    const float* wrow = conv_w + (size_t)n * J_;
    const float* xb = x + (size_t)b * J_ * 3;
    float t0 = 0.f, t1 = 0.f, t2 = 0.f, s = 0.f;
    for (int j = t; j < J_; j += 256) {
        float w = wrow[j];
        s  += w;
        t0 += w * xb[3*j+0];
        t1 += w * xb[3*j+1];
        t2 += w * xb[3*j+2];
    }
    __shared__ float red[16];
    #pragma unroll
    for (int off = 32; off > 0; off >>= 1) {
        t0 += __shfl_down(t0, off, 64);
        t1 += __shfl_down(t1, off, 64);
        t2 += __shfl_down(t2, off, 64);
        s  += __shfl_down(s,  off, 64);
    }
    const int lane = t & 63, wid = t >> 6;
    if (lane == 0) { red[wid*4+0]=t0; red[wid*4+1]=t1; red[wid*4+2]=t2; red[wid*4+3]=s; }
    __syncthreads();
    t0 = red[0]+red[4]+red[8]+red[12];
    t1 = red[1]+red[5]+red[9]+red[13];
    t2 = red[2]+red[6]+red[10]+red[14];
    s  = red[3]+red[7]+red[11]+red[15];
    __syncthreads();

    float val = t0*emb_w[t] + t1*emb_w[D_+t] + t2*emb_w[2*D_+t]
              + s*emb_b[t] + conv_b[n] + pos_emb[(size_t)n*D_ + t];

    float sv = val, sq = val*val;
    #pragma unroll
    for (int off = 32; off > 0; off >>= 1) {
        sv += __shfl_down(sv, off, 64);
        sq += __shfl_down(sq, off, 64);
    }
    if (lane == 0) { red[wid*2]=sv; red[wid*2+1]=sq; }
    __syncthreads();
    sv = red[0]+red[2]+red[4]+red[6];
    sq = red[1]+red[3]+red[5]+red[7];
    float mu   = sv * (1.f/D_);
    float var  = sq * (1.f/D_) - mu*mu;
    float rstd = rsqrtf(fmaxf(var, 0.f) + 1e-5f);
    hout[((size_t)(b*N_ + n))*D_ + t] = (val - mu)*rstd*g[t] + beta[t];
}

// ---------------------------------------------------------------------------
// Row LayerNorm (rows of 256) fp32 -> bf16
// ---------------------------------------------------------------------------
__global__ __launch_bounds__(256) void ln_bf_kernel(
    const float* __restrict__ in, short* __restrict__ outp,
    const float* __restrict__ g, const float* __restrict__ beta)
{
    const int row = blockIdx.x, t = threadIdx.x;
    float v = in[(size_t)row*D_ + t];
    float sv = v, sq = v*v;
    #pragma unroll
    for (int off = 32; off > 0; off >>= 1) {
        sv += __shfl_down(sv, off, 64);
        sq += __shfl_down(sq, off, 64);
    }
    __shared__ float red[8];
    const int lane = t & 63, wid = t >> 6;
    if (lane == 0) { red[wid*2]=sv; red[wid*2+1]=sq; }
    __syncthreads();
    sv = red[0]+red[2]+red[4]+red[6];
    sq = red[1]+red[3]+red[5]+red[7];
    float mu   = sv * (1.f/D_);
    float var  = sq * (1.f/D_) - mu*mu;
    float rstd = rsqrtf(fmaxf(var, 0.f) + 1e-5f);
    outp[(size_t)row*D_ + t] = f2bf((v - mu)*rstd*g[t] + beta[t]);
}

// ---------------------------------------------------------------------------
// Tiled transpose-convert: out_bf16[C][R] = (in_f32[R][C])^T, R,C % 32 == 0
// ---------------------------------------------------------------------------
__global__ __launch_bounds__(256) void tcvt_kernel(
    const float* __restrict__ in, short* __restrict__ outp,
    int R, int C, long inZ, long outZ)
{
    in   += (size_t)blockIdx.z * inZ;
    outp += (size_t)blockIdx.z * outZ;
    __shared__ float tile[32][33];
    const int c0 = blockIdx.x * 32, r0 = blockIdx.y * 32;
    const int t = threadIdx.x;
    const int row = t >> 3, c4 = (t & 7) * 4;
    f4 v = *(const f4*)&in[(size_t)(r0 + row)*C + c0 + c4];
    tile[row][c4+0] = v.x; tile[row][c4+1] = v.y;
    tile[row][c4+2] = v.z; tile[row][c4+3] = v.w;
    __syncthreads();
    const int oc = t >> 3, r4 = (t & 7) * 4;
    short* dst = &outp[(size_t)(c0 + oc)*R + r0 + r4];
    #pragma unroll
    for (int j = 0; j < 4; j++) dst[j] = f2bf(tile[r4 + j][oc]);
}

// straight fp32 -> bf16 convert, grid*256*8 == n exactly
__global__ __launch_bounds__(256) void cvt_kernel(
    const float* __restrict__ in, short* __restrict__ outp)
{
    const size_t i = ((size_t)blockIdx.x * 256 + threadIdx.x) * 8;
    f4 a = *(const f4*)&in[i];
    f4 b = *(const f4*)&in[i + 4];
    s16x8 s;
    s[0]=f2bf(a.x); s[1]=f2bf(a.y); s[2]=f2bf(a.z); s[3]=f2bf(a.w);
    s[4]=f2bf(b.x); s[5]=f2bf(b.y); s[6]=f2bf(b.z); s[7]=f2bf(b.w);
    *(s16x8*)&outp[i] = s;
}

// ---------------------------------------------------------------------------
// bf16 MFMA GEMM: C[M,N] = A[M,K] @ B[K,N], Bt given TRANSPOSED [N][K].
// 128x128 tile, BK=32, 4 waves (2x2), global_load_lds staging (m97 pattern).
// A buffer must be readable up to ceil(M/128)*128 rows (padding in ws).
// ---------------------------------------------------------------------------
template<int BIAS_COL, int BIAS_ROW, int GELU, int RESID, int OUT_BF16>
__global__ __launch_bounds__(256) void gemm_bf16_kernel(
    const short* __restrict__ A, int lda, long sA,
    const short* __restrict__ Bt, int ldb, long sB,
    void* __restrict__ Cv, int ldc, long sC,
    const float* __restrict__ bias, long sBias,
    int M, int K)
{
    const int z = blockIdx.z;
    A  += (size_t)z * sA;
    Bt += (size_t)z * sB;
    const int m0 = blockIdx.y * 128, n0 = blockIdx.x * 128;
    const int t = threadIdx.x;
    const int lane = t & 63, w = t >> 6;
    const int wm = w >> 1, wn = w & 1;

    __shared__ short As[128*32];
    __shared__ short Bs[128*32];

    fx4 acc[4][4];
    #pragma unroll
    for (int i = 0; i < 4; i++)
        #pragma unroll
        for (int j = 0; j < 4; j++)
            acc[i][j] = (fx4){0.f, 0.f, 0.f, 0.f};

    const int srow = lane >> 2, scol = (lane & 3) * 8;   // staging src coords
    const int fr = lane & 15, fg = (lane >> 4) * 8;      // fragment row, k-grp

    for (int k0 = 0; k0 < K; k0 += 32) {
        __syncthreads();       // prev-iter LDS readers done
        #pragma unroll
        for (int c = 0; c < 2; c++) {
            const int r = w*16 + c*64;
            gld16(&As[r*32], &A [(size_t)(m0 + r + srow)*lda + k0 + scol]);
            gld16(&Bs[r*32], &Bt[(size_t)(n0 + r + srow)*ldb + k0 + scol]);
        }
        __syncthreads();       // vmcnt drained by compiler before barrier

        s16x8 af[4], bfr[4];
        #pragma unroll
        for (int i = 0; i < 4; i++) {
            af[i]  = *(const s16x8*)&As[(wm*64 + i*16 + fr)*32 + fg];
            bfr[i] = *(const s16x8*)&Bs[(wn*64 + i*16 + fr)*32 + fg];
        }
        #pragma unroll
        for (int i = 0; i < 4; i++)
            #pragma unroll
            for (int j = 0; j < 4; j++)
                acc[i][j] = __builtin_amdgcn_mfma_f32_16x16x32_bf16(
                                af[i], bfr[j], acc[i][j], 0, 0, 0);
    }

    const int cr = (lane >> 4) * 4, cc = lane & 15;
    #pragma unroll
    for (int i = 0; i < 4; i++) {
        #pragma unroll
        for (int j = 0; j < 4; j++) {
            const int gcol = n0 + wn*64 + j*16 + cc;
            #pragma unroll
            for (int r = 0; r < 4; r++) {
                const int grow = m0 + wm*64 + i*16 + cr + r;
                if (grow >= M) continue;
                float v = acc[i][j][r];
                if (BIAS_COL) v += bias[(size_t)z*sBias + gcol];
                if (BIAS_ROW) v += bias[(size_t)z*sBias + grow];
                if (GELU)     v = gelu_f(v);
                if (OUT_BF16) {
                    short* C = (short*)Cv + (size_t)z*sC;
                    C[(size_t)grow*ldc + gcol] = f2bf(v);
                } else {
                    float* C = (float*)Cv + (size_t)z*sC;
                    float* cp = &C[(size_t)grow*ldc + gcol];
                    float o = v;
                    if (RESID) o += *cp;
                    *cp = o;
                }
            }
        }
    }
}

// ---------------------------------------------------------------------------
// MFMA flash attention (unchanged from round 5 — verified passing).
// ---------------------------------------------------------------------------
__global__ __launch_bounds__(256) void attn_mfma_kernel(
    const short* __restrict__ qkv,   // [B,N,1536] bf16, [q|k|v], head at h*64
    short* __restrict__ o)           // [B,N,512] bf16
{
    const int q0 = blockIdx.x * 128;
    const int head = blockIdx.y;
    const int b = blockIdx.z;
    const int t = threadIdx.x;
    const int lane = t & 63, wq = t >> 6;
    const int g = lane >> 4, i16 = lane & 15;

    __shared__ short Kl[64*64];
    __shared__ short Vtl[64*64];
    __shared__ short Pl[128*64];
    char* const Kb = (char*)Kl;
    char* const Vb = (char*)Vtl;
    char* const Pb = (char*)Pl;

    s16x8 qreg[2][2];
    #pragma unroll
    for (int qf = 0; qf < 2; qf++) {
        const int qg = q0 + wq*32 + i16 + 16*qf;
        const short* qp = qkv + (size_t)(b*N_ + qg)*1536 + head*DH_;
        #pragma unroll
        for (int ks = 0; ks < 2; ks++)
            qreg[qf][ks] = *(const s16x8*)&qp[8*g + 32*ks];
    }

    fx4 oacc[4][2];
    #pragma unroll
    for (int df = 0; df < 4; df++)
        #pragma unroll
        for (int qf = 0; qf < 2; qf++)
            oacc[df][qf] = (fx4){0.f, 0.f, 0.f, 0.f};
    float mst[2] = {-INFINITY, -INFINITY};
    float lst[2] = {0.f, 0.f};

    const int sr = t >> 2, scol = (t & 3) * 16;
    const int swr = (sr & 7) << 4;
    const int qrow0 = wq*32 + i16, qrow1 = qrow0 + 16;
    const int swq0 = (qrow0 & 7) << 4, swq1 = (qrow1 & 7) << 4;

    for (int kt = 0; kt < N_/64; ++kt) {
        const short* kp = qkv + (size_t)(b*N_ + kt*64 + sr)*1536 + INNER_ + head*DH_ + scol;
        s16x8 k0 = *(const s16x8*)kp;
        s16x8 k1 = *(const s16x8*)(kp + 8);
        s16x8 v0 = *(const s16x8*)(kp + INNER_);
        s16x8 v1 = *(const s16x8*)(kp + INNER_ + 8);
        __syncthreads();
        *(s16x8*)(Kb + sr*128 + ((2*scol)      ^ swr)) = k0;
        *(s16x8*)(Kb + sr*128 + ((2*scol + 16) ^ swr)) = k1;
        #pragma unroll
        for (int j = 0; j < 8; j++) {
            *(short*)(Vb + (scol+j)*128   + ((2*sr) ^ (j<<4))) = v0[j];
            *(short*)(Vb + (scol+8+j)*128 + ((2*sr) ^ (j<<4))) = v1[j];
        }
        __syncthreads();

        fx4 sacc[4][2];
        #pragma unroll
        for (int kvf = 0; kvf < 4; kvf++)
            #pragma unroll
            for (int qf = 0; qf < 2; qf++)
                sacc[kvf][qf] = (fx4){0.f, 0.f, 0.f, 0.f};
        #pragma unroll
        for (int ks = 0; ks < 2; ks++) {
            #pragma unroll
            for (int kvf = 0; kvf < 4; kvf++) {
                const int kv = i16 + 16*kvf;
                s16x8 ka = *(const s16x8*)(Kb + kv*128 + ((16*g + 64*ks) ^ ((kv&7)<<4)));
                #pragma unroll
                for (int qf = 0; qf < 2; qf++)
                    sacc[kvf][qf] = __builtin_amdgcn_mfma_f32_16x16x32_bf16(
                                        ka, qreg[qf][ks], sacc[kvf][qf], 0, 0, 0);
            }
        }

        #pragma unroll
        for (int qf = 0; qf < 2; qf++) {
            float sv[16];
            #pragma unroll
            for (int kvf = 0; kvf < 4; kvf++)
                #pragma unroll
                for (int r = 0; r < 4; r++)
                    sv[kvf*4+r] = sacc[kvf][qf][r] * 0.125f;
            float tm = sv[0];
            #pragma unroll
            for (int k = 1; k < 16; k++) tm = fmaxf(tm, sv[k]);
            tm = fmaxf(tm, __shfl_xor(tm, 16, 64));
            tm = fmaxf(tm, __shfl_xor(tm, 32, 64));
            const float mn  = fmaxf(qf ? mst[1] : mst[0], tm);
            const float scl = __expf((qf ? mst[1] : mst[0]) - mn);
            float rs = 0.f;
            float p[16];
            #pragma unroll
            for (int k = 0; k < 16; k++) { p[k] = __expf(sv[k] - mn); rs += p[k]; }
            rs += __shfl_xor(rs, 16, 64);
            rs += __shfl_xor(rs, 32, 64);
            if (qf) { lst[1] = lst[1]*scl + rs; mst[1] = mn; }
            else    { lst[0] = lst[0]*scl + rs; mst[0] = mn; }
            #pragma unroll
            for (int df = 0; df < 4; df++) {
                oacc[df][qf][0] *= scl; oacc[df][qf][1] *= scl;
                oacc[df][qf][2] *= scl; oacc[df][qf][3] *= scl;
            }
            const int qr = qf ? qrow1 : qrow0;
            const int sq = qf ? swq1 : swq0;
            #pragma unroll
            for (int kvf = 0; kvf < 4; kvf++) {
                uint2 wv;
                wv.x = (unsigned int)(unsigned short)f2bf(p[4*kvf+0]) |
                       ((unsigned int)(unsigned short)f2bf(p[4*kvf+1]) << 16);
                wv.y = (unsigned int)(unsigned short)f2bf(p[4*kvf+2]) |
                       ((unsigned int)(unsigned short)f2bf(p[4*kvf+3]) << 16);
                *(uint2*)(Pb + qr*128 + ((8*g + 32*kvf) ^ sq)) = wv;
            }
        }

        asm volatile("s_waitcnt lgkmcnt(0)" ::: "memory");
        __builtin_amdgcn_sched_barrier(0);

        #pragma unroll
        for (int ks = 0; ks < 2; ks++) {
            s16x8 pf0 = *(const s16x8*)(Pb + qrow0*128 + ((16*g + 64*ks) ^ swq0));
            s16x8 pf1 = *(const s16x8*)(Pb + qrow1*128 + ((16*g + 64*ks) ^ swq1));
            #pragma unroll
            for (int df = 0; df < 4; df++) {
                const int dh = i16 + 16*df;
                s16x8 va = *(const s16x8*)(Vb + dh*128 + ((16*g + 64*ks) ^ ((dh&7)<<4)));
                oacc[df][0] = __builtin_amdgcn_mfma_f32_16x16x32_bf16(va, pf0, oacc[df][0], 0, 0, 0);
                oacc[df][1] = __builtin_amdgcn_mfma_f32_16x16x32_bf16(va, pf1, oacc[df][1], 0, 0, 0);
            }
        }
    }

    const float inv0 = 1.f / lst[0], inv1 = 1.f / lst[1];
    #pragma unroll
    for (int df = 0; df < 4; df++)
        #pragma unroll
        for (int r = 0; r < 4; r++) {
            const int dh = 4*g + r + 16*df;
            *(short*)(Pb + qrow0*128 + ((2*dh) ^ swq0)) = f2bf(oacc[df][0][r]*inv0);
            *(short*)(Pb + qrow1*128 + ((2*dh) ^ swq1)) = f2bf(oacc[df][1][r]*inv1);
        }
    __syncthreads();
    {
        const int qr = t >> 1, h2 = t & 1;
        const int sq = (qr & 7) << 4;
        short* op = o + (size_t)(b*N_ + q0 + qr)*INNER_ + head*DH_ + 32*h2;
        #pragma unroll
        for (int e = 0; e < 4; e++) {
            s16x8 vv = *(const s16x8*)(Pb + qr*128 + ((64*h2 + 16*e) ^ sq));
            *(s16x8*)&op[8*e] = vv;
        }
    }
}

// ---------------------------------------------------------------------------
// Fully-fused gaussian heads: per block a 128(m) x 256(n) tile of
// hid = gelu(u[b] @ w1[k] + b1[k]) computed in registers, then the w2[k]
// contraction in-register (shuffle-reduce over the 16 col-lanes) and a
// cross-wave LDS reduce. One dispatch replaces 5 GEMMs + 5 phase-2 kernels;
// hid never touches global memory.  grid(MP/128, B, 5), 512 threads (8 waves).
// ---------------------------------------------------------------------------
__global__ __launch_bounds__(512) void heads_fused_kernel(
    const short* __restrict__ u,      // [MP][1024] bf16; batch b at col b*256
    const short* __restrict__ w1T,    // [5][256][256] bf16 ([out][in] per head)
    const float* __restrict__ b1,     // [5][256]
    const float* __restrict__ w2,     // [5][256][4]
    const float* __restrict__ b2,     // [5][4]
    float* __restrict__ outp)         // [B][M][14]
{
    const int m0 = blockIdx.x * 128;
    const int b  = blockIdx.y;
    const int k  = blockIdx.z;
    const int t  = threadIdx.x;
    const int lane = t & 63, w = t >> 6;
    const int wm = w >> 2, wn = w & 3;

    __shared__ short As[128*32];
    __shared__ short Bs[256*32];
    __shared__ float w2s[1024];
    __shared__ float b1s[256];
    __shared__ float red4[4][128][4];

    if (t < 256) b1s[t] = b1[k*256 + t];
    w2s[t]       = w2[k*1024 + t];
    w2s[t + 512] = w2[k*1024 + t + 512];

    fx4 acc[4][4];
    #pragma unroll
    for (int i = 0; i < 4; i++)
        #pragma unroll
        for (int j = 0; j < 4; j++)
            acc[i][j] = (fx4){0.f, 0.f, 0.f, 0.f};

    const short* Ab = u + (size_t)b * 256;
    const short* Bb = w1T + (size_t)k * 65536;
    const int srow = lane >> 2, scol = (lane & 3) * 8;
    const int fr = lane & 15, fg = (lane >> 4) * 8;

    for (int k0 = 0; k0 < 256; k0 += 32) {
        __syncthreads();
        {   // A: 128 rows, 8 waves x 16
            const int r = w*16;
            gld16(&As[r*32], &Ab[(size_t)(m0 + r + srow)*1024 + k0 + scol]);
            // B: 256 rows, 8 waves x 2 x 16
            gld16(&Bs[r*32],         &Bb[(size_t)(r + srow)*256 + k0 + scol]);
            gld16(&Bs[(128+r)*32],   &Bb[(size_t)(128 + r + srow)*256 + k0 + scol]);
        }
        __syncthreads();

        s16x8 af[4], bfr[4];
        #pragma unroll
        for (int i = 0; i < 4; i++) {
            af[i]  = *(const s16x8*)&As[(wm*64 + i*16 + fr)*32 + fg];
            bfr[i] = *(const s16x8*)&Bs[(wn*64 + i*16 + fr)*32 + fg];
        }
        #pragma unroll
        for (int i = 0; i < 4; i++)
            #pragma unroll
            for (int j = 0; j < 4; j++)
                acc[i][j] = __builtin_amdgcn_mfma_f32_16x16x32_bf16(
                                af[i], bfr[j], acc[i][j], 0, 0, 0);
    }

    // phase 2: hid = gelu(acc + b1); p[i][r][o] = sum_j hid * w2[col][o]
    const int cr = (lane >> 4) * 4, cc = lane & 15;
    float p[4][4][4];
    #pragma unroll
    for (int i = 0; i < 4; i++)
        #pragma unroll
        for (int r = 0; r < 4; r++)
            #pragma unroll
            for (int o = 0; o < 4; o++) p[i][r][o] = 0.f;

    #pragma unroll
    for (int i = 0; i < 4; i++) {
        #pragma unroll
        for (int j = 0; j < 4; j++) {
            const int col = wn*64 + j*16 + cc;
            const float bb = b1s[col];
            const float* wv = &w2s[col*4];
            #pragma unroll
            for (int r = 0; r < 4; r++) {
                const float hv = gelu_f(acc[i][j][r] + bb);
                #pragma unroll
                for (int o = 0; o < 4; o++) p[i][r][o] += hv * wv[o];
            }
        }
    }
    // reduce over the 16 cc-lanes (cols), then stash per-wave partials
    #pragma unroll
    for (int i = 0; i < 4; i++)
        #pragma unroll
        for (int r = 0; r < 4; r++)
            #pragma unroll
            for (int o = 0; o < 4; o++) {
                float v = p[i][r][o];
                v += __shfl_xor(v, 1, 64);
                v += __shfl_xor(v, 2, 64);
                v += __shfl_xor(v, 4, 64);
                v += __shfl_xor(v, 8, 64);
                p[i][r][o] = v;
            }
    if (cc == 0) {
        #pragma unroll
        for (int i = 0; i < 4; i++)
            #pragma unroll
            for (int r = 0; r < 4; r++)
                #pragma unroll
                for (int o = 0; o < 4; o++)
                    red4[wn][wm*64 + i*16 + cr + r][o] = p[i][r][o];
    }
    __syncthreads();

    const int koff = (k==0) ? 0 : (k==1) ? 3 : (k==2) ? 4 : (k==3) ? 7 : 11;
    const int kcnt = (k==1) ? 1 : (k==3) ? 4 : 3;
    {
        const int row = t >> 2, o = t & 3;
        const int m = m0 + row;
        if (o < kcnt && m < M_) {
            float v = red4[0][row][o] + red4[1][row][o]
                    + red4[2][row][o] + red4[3][row][o] + b2[k*4 + o];
            outp[((size_t)b*M_ + m)*14 + koff + o] = v;
        }
    }
}

// ---------------------------------------------------------------------------
extern "C" void kernel_launch(void* const* d_in, const int* in_sizes, int n_in,
                              void* d_out, int out_size, void* d_ws, size_t ws_size,
                              hipStream_t stream)
{
    const float* x          = (const float*)d_in[0];
    const float* pre_emb_w  = (const float*)d_in[1];
    const float* pre_emb_b  = (const float*)d_in[2];
    const float* pre_conv_w = (const float*)d_in[3];
    const float* pre_conv_b = (const float*)d_in[4];
    const float* pos_emb    = (const float*)d_in[5];
    const float* pre_norm_g = (const float*)d_in[6];
    const float* pre_norm_b = (const float*)d_in[7];
    const float* ln1_g      = (const float*)d_in[8];
    const float* ln1_b      = (const float*)d_in[9];
    const float* qkv_w      = (const float*)d_in[10];
    const float* out_w      = (const float*)d_in[11];
    const float* out_b      = (const float*)d_in[12];
    const float* ln2_g      = (const float*)d_in[13];
    const float* ln2_b      = (const float*)d_in[14];
    const float* ff_w1      = (const float*)d_in[15];
    const float* ff_b1      = (const float*)d_in[16];
    const float* ff_w2      = (const float*)d_in[17];
    const float* ff_b2      = (const float*)d_in[18];
    const float* up_w       = (const float*)d_in[19];
    const float* up_b       = (const float*)d_in[20];
    const float* heads_w1   = (const float*)d_in[21];
    const float* heads_b1   = (const float*)d_in[22];
    const float* heads_w2   = (const float*)d_in[23];
    const float* heads_b2   = (const float*)d_in[24];
    float* out = (float*)d_out;

    // ---- workspace layout (bytes), total ~94 MiB --------------------------
    char* ws = (char*)d_ws;
    float* h      = (float*)(ws);                 //  8,388,608 (fp32 residual)
    char*  R2     = ws + 8388608;                 // 56,623,104 region
    short* y_bf   = (short*)(R2);                 //  4,194,304
    short* qkv_bf = (short*)(R2 + 4194304);       // 25,165,824
    short* ffmid  = qkv_bf;                       // alias (disjoint lifetime)
    short* obuf   = (short*)(R2 + 29360128);      //  8,388,608
    short* qkvT   = (short*)(R2 + 37748736);      //  3,145,728
    short* outT   = (short*)(R2 + 40894464);      //  1,048,576
    short* ff1T   = (short*)(R2 + 41943040);      //  2,097,152
    short* ff2T   = (short*)(R2 + 44040192);      //  2,097,152
    short* upw_bf = (short*)(R2);                 // aliases R2 post-layers (MP rows readable)
    short* hT     = (short*)(ws + 65011712);      //  4,194,304 ([4][256][2048] = [1024][2048])
    short* u_bf   = (short*)(ws + 69206016);      // 28,311,552 ([MP][1024])
    short* w1T    = (short*)(ws + 97517568);      //    655,360

    // ---- weight transpose-converts (fp32 [K][N] -> bf16 [N][K]) -----------
    tcvt_kernel<<<dim3(1536/32,  256/32, 4), 256, 0, stream>>>(qkv_w,    qkvT, 256, 1536, 256L*1536, 1536L*256);
    tcvt_kernel<<<dim3( 256/32,  512/32, 4), 256, 0, stream>>>(out_w,    outT, 512,  256, 512L*256,  256L*512);
    tcvt_kernel<<<dim3(1024/32,  256/32, 4), 256, 0, stream>>>(ff_w1,    ff1T, 256, 1024, 256L*1024, 1024L*256);
    tcvt_kernel<<<dim3( 256/32, 1024/32, 4), 256, 0, stream>>>(ff_w2,    ff2T, 1024, 256, 1024L*256, 256L*1024);
    tcvt_kernel<<<dim3( 256/32,  256/32, 5), 256, 0, stream>>>(heads_w1, w1T,  256,  256, 256L*256,  256L*256);

    embed_ln_kernel<<<dim3(N_, B_), 256, 0, stream>>>(
        x, pre_emb_w, pre_emb_b, pre_conv_w, pre_conv_b, pos_emb,
        pre_norm_g, pre_norm_b, h);

    const int rows = B_ * N_;   // 8192
    for (int i = 0; i < L_; i++) {
        ln_bf_kernel<<<rows, 256, 0, stream>>>(h, y_bf, ln1_g + i*D_, ln1_b + i*D_);
        gemm_bf16_kernel<0,0,0,0,1><<<dim3(12, rows/128, 1), 256, 0, stream>>>(
            y_bf, 256, 0, qkvT + (size_t)i*1536*256, 256, 0,
            qkv_bf, 1536, 0, nullptr, 0, rows, 256);
        attn_mfma_kernel<<<dim3(N_/128, H_, B_), 256, 0, stream>>>(qkv_bf, obuf);
        gemm_bf16_kernel<1,0,0,1,0><<<dim3(2, rows/128, 1), 256, 0, stream>>>(
            obuf, 512, 0, outT + (size_t)i*256*512, 512, 0,
            h, 256, 0, out_b + i*D_, 0, rows, 512);
        ln_bf_kernel<<<rows, 256, 0, stream>>>(h, y_bf, ln2_g + i*D_, ln2_b + i*D_);
        gemm_bf16_kernel<1,0,1,0,1><<<dim3(8, rows/128, 1), 256, 0, stream>>>(
            y_bf, 256, 0, ff1T + (size_t)i*1024*256, 256, 0,
            ffmid, 1024, 0, ff_b1 + i*FF_, 0, rows, 256);
        gemm_bf16_kernel<1,0,0,1,0><<<dim3(2, rows/128, 1), 256, 0, stream>>>(
            ffmid, 1024, 0, ff2T + (size_t)i*256*1024, 1024, 0,
            h, 256, 0, ff_b2 + i*D_, 0, rows, 1024);
    }

    // up_w -> bf16
    cvt_kernel<<<13780, 256, 0, stream>>>(up_w, upw_bf);
    // h transpose per batch: [2048,256] -> bf16 [256,2048]; flat = [1024][2048]
    tcvt_kernel<<<dim3(256/32, 2048/32, 4), 256, 0, stream>>>(h, hT, 2048, 256, 2048L*256, 256L*2048);
    // upsample, batches merged into N: u[m][b*256+d], single GEMM N=1024 K=2048
    gemm_bf16_kernel<0,1,0,0,1><<<dim3(8, MP_/128, 1), 256, 0, stream>>>(
        upw_bf, 2048, 0, hT, 2048, 0,
        u_bf, 1024, 0, up_b, 0, M_, 2048);

    // fully-fused gaussian heads
    heads_fused_kernel<<<dim3(MP_/128, B_, 5), 512, 0, stream>>>(
        u_bf, w1T, heads_b1, heads_w2, heads_b2, out);
}

// Round 7
// 1349.812 us; speedup vs baseline: 1.1893x; 1.1893x over previous
//
#include <hip/hip_runtime.h>
#include <math.h>

#define B_ 4
#define J_ 6890
#define D_ 256
#define L_ 4
#define H_ 8
#define DH_ 64
#define INNER_ 512
#define N_ 2048
#define FF_ 1024
#define M_ 13780
#define MP_ 13824   // M padded to multiple of 128

typedef float4 f4;
typedef __attribute__((ext_vector_type(8))) short s16x8;   // 8 bf16 (4 VGPRs)
typedef __attribute__((ext_vector_type(4))) float fx4;     // MFMA C/D

__device__ __forceinline__ float b2f(short s) {
    return __uint_as_float(((unsigned int)(unsigned short)s) << 16);
}
__device__ __forceinline__ short f2bf(float f) {   // RNE
    unsigned int u = __float_as_uint(f);
    unsigned int r = (u + 0x7FFFu + ((u >> 16) & 1u)) >> 16;
    return (short)r;
}
__device__ __forceinline__ float gelu_f(float v) {
    return 0.5f * v * (1.0f + erff(v * 0.70710678118654752440f));
}

// async global->LDS, 16B/lane. LDS dest: wave-uniform base + lane*16 (m97).
__device__ __forceinline__ void gld16(void* lds, const void* g) {
    __builtin_amdgcn_global_load_lds(
        (const __attribute__((address_space(1))) void*)g,
        (__attribute__((address_space(3))) void*)lds, 16, 0, 0);
}

// ---------------------------------------------------------------------------
// Fused token-embed + 1x1 conv (J->N) + pos-emb + pre-LN.  (fp32)
// ---------------------------------------------------------------------------
__global__ __launch_bounds__(256) void embed_ln_kernel(
    const float* __restrict__ x, const float* __restrict__ emb_w,
    const float* __restrict__ emb_b, const float* __restrict__ conv_w,
    const float* __restrict__ conv_b, const float* __restrict__ pos_emb,
    const float* __restrict__ g, const float* __restrict__ beta,
    float* __restrict__ hout)
{
    const int n = blockIdx.x, b = blockIdx.y, t = threadIdx.x;
    const float* wrow = conv_w + (size_t)n * J_;
    const float* xb = x + (size_t)b * J_ * 3;
    float t0 = 0.f, t1 = 0.f, t2 = 0.f, s = 0.f;
    for (int j = t; j < J_; j += 256) {
        float w = wrow[j];
        s  += w;
        t0 += w * xb[3*j+0];
        t1 += w * xb[3*j+1];
        t2 += w * xb[3*j+2];
    }
    __shared__ float red[16];
    #pragma unroll
    for (int off = 32; off > 0; off >>= 1) {
        t0 += __shfl_down(t0, off, 64);
        t1 += __shfl_down(t1, off, 64);
        t2 += __shfl_down(t2, off, 64);
        s  += __shfl_down(s,  off, 64);
    }
    const int lane = t & 63, wid = t >> 6;
    if (lane == 0) { red[wid*4+0]=t0; red[wid*4+1]=t1; red[wid*4+2]=t2; red[wid*4+3]=s; }
    __syncthreads();
    t0 = red[0]+red[4]+red[8]+red[12];
    t1 = red[1]+red[5]+red[9]+red[13];
    t2 = red[2]+red[6]+red[10]+red[14];
    s  = red[3]+red[7]+red[11]+red[15];
    __syncthreads();

    float val = t0*emb_w[t] + t1*emb_w[D_+t] + t2*emb_w[2*D_+t]
              + s*emb_b[t] + conv_b[n] + pos_emb[(size_t)n*D_ + t];

    float sv = val, sq = val*val;
    #pragma unroll
    for (int off = 32; off > 0; off >>= 1) {
        sv += __shfl_down(sv, off, 64);
        sq += __shfl_down(sq, off, 64);
    }
    if (lane == 0) { red[wid*2]=sv; red[wid*2+1]=sq; }
    __syncthreads();
    sv = red[0]+red[2]+red[4]+red[6];
    sq = red[1]+red[3]+red[5]+red[7];
    float mu   = sv * (1.f/D_);
    float var  = sq * (1.f/D_) - mu*mu;
    float rstd = rsqrtf(fmaxf(var, 0.f) + 1e-5f);
    hout[((size_t)(b*N_ + n))*D_ + t] = (val - mu)*rstd*g[t] + beta[t];
}

// ---------------------------------------------------------------------------
// Row LayerNorm (rows of 256) fp32 -> bf16
// ---------------------------------------------------------------------------
__global__ __launch_bounds__(256) void ln_bf_kernel(
    const float* __restrict__ in, short* __restrict__ outp,
    const float* __restrict__ g, const float* __restrict__ beta)
{
    const int row = blockIdx.x, t = threadIdx.x;
    float v = in[(size_t)row*D_ + t];
    float sv = v, sq = v*v;
    #pragma unroll
    for (int off = 32; off > 0; off >>= 1) {
        sv += __shfl_down(sv, off, 64);
        sq += __shfl_down(sq, off, 64);
    }
    __shared__ float red[8];
    const int lane = t & 63, wid = t >> 6;
    if (lane == 0) { red[wid*2]=sv; red[wid*2+1]=sq; }
    __syncthreads();
    sv = red[0]+red[2]+red[4]+red[6];
    sq = red[1]+red[3]+red[5]+red[7];
    float mu   = sv * (1.f/D_);
    float var  = sq * (1.f/D_) - mu*mu;
    float rstd = rsqrtf(fmaxf(var, 0.f) + 1e-5f);
    outp[(size_t)row*D_ + t] = f2bf((v - mu)*rstd*g[t] + beta[t]);
}

// ---------------------------------------------------------------------------
// Tiled transpose-convert: out_bf16[C][R] = (in_f32[R][C])^T, R,C % 32 == 0
// ---------------------------------------------------------------------------
__global__ __launch_bounds__(256) void tcvt_kernel(
    const float* __restrict__ in, short* __restrict__ outp,
    int R, int C, long inZ, long outZ)
{
    in   += (size_t)blockIdx.z * inZ;
    outp += (size_t)blockIdx.z * outZ;
    __shared__ float tile[32][33];
    const int c0 = blockIdx.x * 32, r0 = blockIdx.y * 32;
    const int t = threadIdx.x;
    const int row = t >> 3, c4 = (t & 7) * 4;
    f4 v = *(const f4*)&in[(size_t)(r0 + row)*C + c0 + c4];
    tile[row][c4+0] = v.x; tile[row][c4+1] = v.y;
    tile[row][c4+2] = v.z; tile[row][c4+3] = v.w;
    __syncthreads();
    const int oc = t >> 3, r4 = (t & 7) * 4;
    short* dst = &outp[(size_t)(c0 + oc)*R + r0 + r4];
    #pragma unroll
    for (int j = 0; j < 4; j++) dst[j] = f2bf(tile[r4 + j][oc]);
}

// straight fp32 -> bf16 convert, grid*256*8 == n exactly
__global__ __launch_bounds__(256) void cvt_kernel(
    const float* __restrict__ in, short* __restrict__ outp)
{
    const size_t i = ((size_t)blockIdx.x * 256 + threadIdx.x) * 8;
    f4 a = *(const f4*)&in[i];
    f4 b = *(const f4*)&in[i + 4];
    s16x8 s;
    s[0]=f2bf(a.x); s[1]=f2bf(a.y); s[2]=f2bf(a.z); s[3]=f2bf(a.w);
    s[4]=f2bf(b.x); s[5]=f2bf(b.y); s[6]=f2bf(b.z); s[7]=f2bf(b.w);
    *(s16x8*)&outp[i] = s;
}

// ---------------------------------------------------------------------------
// bf16 MFMA GEMM: C[M,N] = A[M,K] @ B[K,N], Bt given TRANSPOSED [N][K].
// 128x128 tile, BK=64 (2 barriers per 64-K), 4 waves (2x2).
// Staging: global_load_lds w/ PRE-SWIZZLED SOURCE (m173): linear LDS dest,
// source 16B-chunk = (lane&7)^(lane>>3); frag reads XOR byte^=((row&7)<<4)
// -> conflict-free ds_read_b128 (dword bank = 4*(g ^ (fr&7)), uniform).
// K % 64 == 0 required (all call sites: 256/512/1024/2048).
// ---------------------------------------------------------------------------
template<int BIAS_COL, int BIAS_ROW, int GELU, int RESID, int OUT_BF16>
__global__ __launch_bounds__(256) void gemm_bf16_kernel(
    const short* __restrict__ A, int lda, long sA,
    const short* __restrict__ Bt, int ldb, long sB,
    void* __restrict__ Cv, int ldc, long sC,
    const float* __restrict__ bias, long sBias,
    int M, int K)
{
    const int z = blockIdx.z;
    A  += (size_t)z * sA;
    Bt += (size_t)z * sB;
    const int m0 = blockIdx.y * 128, n0 = blockIdx.x * 128;
    const int t = threadIdx.x;
    const int lane = t & 63, w = t >> 6;
    const int wm = w >> 1, wn = w & 1;

    __shared__ short As[128*64];   // 16 KB, row pitch 64 shorts (128 B)
    __shared__ short Bs[128*64];   // 16 KB

    fx4 acc[4][4];
    #pragma unroll
    for (int i = 0; i < 4; i++)
        #pragma unroll
        for (int j = 0; j < 4; j++)
            acc[i][j] = (fx4){0.f, 0.f, 0.f, 0.f};

    // staging: lane covers row (base + lane>>3), source chunk pre-swizzled
    const int srow = lane >> 3;
    const int scol = ((lane & 7) ^ (lane >> 3)) * 8;
    const int fr = lane & 15, g = lane >> 4;
    const int fswz = (fr & 7) << 3;             // short-offset swizzle term

    for (int k0 = 0; k0 < K; k0 += 64) {
        __syncthreads();       // prev-iter LDS readers done
        #pragma unroll
        for (int c = 0; c < 4; c++) {
            const int r = w*32 + c*8;
            gld16(&As[r*64], &A [(size_t)(m0 + r + srow)*lda + k0 + scol]);
            gld16(&Bs[r*64], &Bt[(size_t)(n0 + r + srow)*ldb + k0 + scol]);
        }
        __syncthreads();       // vmcnt drained by compiler before barrier

        #pragma unroll
        for (int ks = 0; ks < 2; ks++) {
            const int co = (ks*32 + g*8) ^ fswz;
            s16x8 af[4], bfr[4];
            #pragma unroll
            for (int i = 0; i < 4; i++) {
                af[i]  = *(const s16x8*)&As[(wm*64 + i*16 + fr)*64 + co];
                bfr[i] = *(const s16x8*)&Bs[(wn*64 + i*16 + fr)*64 + co];
            }
            #pragma unroll
            for (int i = 0; i < 4; i++)
                #pragma unroll
                for (int j = 0; j < 4; j++)
                    acc[i][j] = __builtin_amdgcn_mfma_f32_16x16x32_bf16(
                                    af[i], bfr[j], acc[i][j], 0, 0, 0);
        }
    }

    const int cr = (lane >> 4) * 4, cc = lane & 15;
    #pragma unroll
    for (int i = 0; i < 4; i++) {
        #pragma unroll
        for (int j = 0; j < 4; j++) {
            const int gcol = n0 + wn*64 + j*16 + cc;
            #pragma unroll
            for (int r = 0; r < 4; r++) {
                const int grow = m0 + wm*64 + i*16 + cr + r;
                if (grow >= M) continue;
                float v = acc[i][j][r];
                if (BIAS_COL) v += bias[(size_t)z*sBias + gcol];
                if (BIAS_ROW) v += bias[(size_t)z*sBias + grow];
                if (GELU)     v = gelu_f(v);
                if (OUT_BF16) {
                    short* C = (short*)Cv + (size_t)z*sC;
                    C[(size_t)grow*ldc + gcol] = f2bf(v);
                } else {
                    float* C = (float*)Cv + (size_t)z*sC;
                    float* cp = &C[(size_t)grow*ldc + gcol];
                    float o = v;
                    if (RESID) o += *cp;
                    *cp = o;
                }
            }
        }
    }
}

// ---------------------------------------------------------------------------
// MFMA flash attention (unchanged — verified passing).
// ---------------------------------------------------------------------------
__global__ __launch_bounds__(256) void attn_mfma_kernel(
    const short* __restrict__ qkv,   // [B,N,1536] bf16, [q|k|v], head at h*64
    short* __restrict__ o)           // [B,N,512] bf16
{
    const int q0 = blockIdx.x * 128;
    const int head = blockIdx.y;
    const int b = blockIdx.z;
    const int t = threadIdx.x;
    const int lane = t & 63, wq = t >> 6;
    const int g = lane >> 4, i16 = lane & 15;

    __shared__ short Kl[64*64];
    __shared__ short Vtl[64*64];
    __shared__ short Pl[128*64];
    char* const Kb = (char*)Kl;
    char* const Vb = (char*)Vtl;
    char* const Pb = (char*)Pl;

    s16x8 qreg[2][2];
    #pragma unroll
    for (int qf = 0; qf < 2; qf++) {
        const int qg = q0 + wq*32 + i16 + 16*qf;
        const short* qp = qkv + (size_t)(b*N_ + qg)*1536 + head*DH_;
        #pragma unroll
        for (int ks = 0; ks < 2; ks++)
            qreg[qf][ks] = *(const s16x8*)&qp[8*g + 32*ks];
    }

    fx4 oacc[4][2];
    #pragma unroll
    for (int df = 0; df < 4; df++)
        #pragma unroll
        for (int qf = 0; qf < 2; qf++)
            oacc[df][qf] = (fx4){0.f, 0.f, 0.f, 0.f};
    float mst[2] = {-INFINITY, -INFINITY};
    float lst[2] = {0.f, 0.f};

    const int sr = t >> 2, scol = (t & 3) * 16;
    const int swr = (sr & 7) << 4;
    const int qrow0 = wq*32 + i16, qrow1 = qrow0 + 16;
    const int swq0 = (qrow0 & 7) << 4, swq1 = (qrow1 & 7) << 4;

    for (int kt = 0; kt < N_/64; ++kt) {
        const short* kp = qkv + (size_t)(b*N_ + kt*64 + sr)*1536 + INNER_ + head*DH_ + scol;
        s16x8 k0 = *(const s16x8*)kp;
        s16x8 k1 = *(const s16x8*)(kp + 8);
        s16x8 v0 = *(const s16x8*)(kp + INNER_);
        s16x8 v1 = *(const s16x8*)(kp + INNER_ + 8);
        __syncthreads();
        *(s16x8*)(Kb + sr*128 + ((2*scol)      ^ swr)) = k0;
        *(s16x8*)(Kb + sr*128 + ((2*scol + 16) ^ swr)) = k1;
        #pragma unroll
        for (int j = 0; j < 8; j++) {
            *(short*)(Vb + (scol+j)*128   + ((2*sr) ^ (j<<4))) = v0[j];
            *(short*)(Vb + (scol+8+j)*128 + ((2*sr) ^ (j<<4))) = v1[j];
        }
        __syncthreads();

        fx4 sacc[4][2];
        #pragma unroll
        for (int kvf = 0; kvf < 4; kvf++)
            #pragma unroll
            for (int qf = 0; qf < 2; qf++)
                sacc[kvf][qf] = (fx4){0.f, 0.f, 0.f, 0.f};
        #pragma unroll
        for (int ks = 0; ks < 2; ks++) {
            #pragma unroll
            for (int kvf = 0; kvf < 4; kvf++) {
                const int kv = i16 + 16*kvf;
                s16x8 ka = *(const s16x8*)(Kb + kv*128 + ((16*g + 64*ks) ^ ((kv&7)<<4)));
                #pragma unroll
                for (int qf = 0; qf < 2; qf++)
                    sacc[kvf][qf] = __builtin_amdgcn_mfma_f32_16x16x32_bf16(
                                        ka, qreg[qf][ks], sacc[kvf][qf], 0, 0, 0);
            }
        }

        #pragma unroll
        for (int qf = 0; qf < 2; qf++) {
            float sv[16];
            #pragma unroll
            for (int kvf = 0; kvf < 4; kvf++)
                #pragma unroll
                for (int r = 0; r < 4; r++)
                    sv[kvf*4+r] = sacc[kvf][qf][r] * 0.125f;
            float tm = sv[0];
            #pragma unroll
            for (int k = 1; k < 16; k++) tm = fmaxf(tm, sv[k]);
            tm = fmaxf(tm, __shfl_xor(tm, 16, 64));
            tm = fmaxf(tm, __shfl_xor(tm, 32, 64));
            const float mn  = fmaxf(qf ? mst[1] : mst[0], tm);
            const float scl = __expf((qf ? mst[1] : mst[0]) - mn);
            float rs = 0.f;
            float p[16];
            #pragma unroll
            for (int k = 0; k < 16; k++) { p[k] = __expf(sv[k] - mn); rs += p[k]; }
            rs += __shfl_xor(rs, 16, 64);
            rs += __shfl_xor(rs, 32, 64);
            if (qf) { lst[1] = lst[1]*scl + rs; mst[1] = mn; }
            else    { lst[0] = lst[0]*scl + rs; mst[0] = mn; }
            #pragma unroll
            for (int df = 0; df < 4; df++) {
                oacc[df][qf][0] *= scl; oacc[df][qf][1] *= scl;
                oacc[df][qf][2] *= scl; oacc[df][qf][3] *= scl;
            }
            const int qr = qf ? qrow1 : qrow0;
            const int sq = qf ? swq1 : swq0;
            #pragma unroll
            for (int kvf = 0; kvf < 4; kvf++) {
                uint2 wv;
                wv.x = (unsigned int)(unsigned short)f2bf(p[4*kvf+0]) |
                       ((unsigned int)(unsigned short)f2bf(p[4*kvf+1]) << 16);
                wv.y = (unsigned int)(unsigned short)f2bf(p[4*kvf+2]) |
                       ((unsigned int)(unsigned short)f2bf(p[4*kvf+3]) << 16);
                *(uint2*)(Pb + qr*128 + ((8*g + 32*kvf) ^ sq)) = wv;
            }
        }

        asm volatile("s_waitcnt lgkmcnt(0)" ::: "memory");
        __builtin_amdgcn_sched_barrier(0);

        #pragma unroll
        for (int ks = 0; ks < 2; ks++) {
            s16x8 pf0 = *(const s16x8*)(Pb + qrow0*128 + ((16*g + 64*ks) ^ swq0));
            s16x8 pf1 = *(const s16x8*)(Pb + qrow1*128 + ((16*g + 64*ks) ^ swq1));
            #pragma unroll
            for (int df = 0; df < 4; df++) {
                const int dh = i16 + 16*df;
                s16x8 va = *(const s16x8*)(Vb + dh*128 + ((16*g + 64*ks) ^ ((dh&7)<<4)));
                oacc[df][0] = __builtin_amdgcn_mfma_f32_16x16x32_bf16(va, pf0, oacc[df][0], 0, 0, 0);
                oacc[df][1] = __builtin_amdgcn_mfma_f32_16x16x32_bf16(va, pf1, oacc[df][1], 0, 0, 0);
            }
        }
    }

    const float inv0 = 1.f / lst[0], inv1 = 1.f / lst[1];
    #pragma unroll
    for (int df = 0; df < 4; df++)
        #pragma unroll
        for (int r = 0; r < 4; r++) {
            const int dh = 4*g + r + 16*df;
            *(short*)(Pb + qrow0*128 + ((2*dh) ^ swq0)) = f2bf(oacc[df][0][r]*inv0);
            *(short*)(Pb + qrow1*128 + ((2*dh) ^ swq1)) = f2bf(oacc[df][1][r]*inv1);
        }
    __syncthreads();
    {
        const int qr = t >> 1, h2 = t & 1;
        const int sq = (qr & 7) << 4;
        short* op = o + (size_t)(b*N_ + q0 + qr)*INNER_ + head*DH_ + 32*h2;
        #pragma unroll
        for (int e = 0; e < 4; e++) {
            s16x8 vv = *(const s16x8*)(Pb + qr*128 + ((64*h2 + 16*e) ^ sq));
            *(s16x8*)&op[8*e] = vv;
        }
    }
}

// ---------------------------------------------------------------------------
// Fused gaussian heads v2. grid(MP/128, B, 5), 512 thr (8 waves, 2x4).
// Phase 1: 128x256 hid tile via MFMA, BK=64 swizzled staging (as gemm).
// Phase 2: gelu'd hid -> LDS bf16 [128][260] (conflict-free reads), then
// thread (row=t>>2, o=t&3) does the 256-col w2 dot directly — no shuffles.
// ---------------------------------------------------------------------------
__global__ __launch_bounds__(512) void heads_fused_kernel(
    const short* __restrict__ u,      // [MP][1024] bf16; batch b at col b*256
    const short* __restrict__ w1T,    // [5][256][256] bf16 ([out][in] per head)
    const float* __restrict__ b1,     // [5][256]
    const float* __restrict__ w2,     // [5][256][4]
    const float* __restrict__ b2,     // [5][4]
    float* __restrict__ outp)         // [B][M][14]
{
    const int m0 = blockIdx.x * 128;
    const int b  = blockIdx.y;
    const int k  = blockIdx.z;
    const int t  = threadIdx.x;
    const int lane = t & 63, w = t >> 6;
    const int wm = w >> 2, wn = w & 3;

    __shared__ char hbuf[67584];          // staging 48KB  ∪  hid 66560B
    short* const As  = (short*)hbuf;            // [128][64]
    short* const Bs  = (short*)(hbuf + 16384);  // [256][64]
    short* const hid = (short*)hbuf;            // [128][260]
    __shared__ float w2s[1024];
    __shared__ float b1s[256];

    if (t < 256) b1s[t] = b1[k*256 + t];
    w2s[t]       = w2[k*1024 + t];
    w2s[t + 512] = w2[k*1024 + t + 512];

    fx4 acc[4][4];
    #pragma unroll
    for (int i = 0; i < 4; i++)
        #pragma unroll
        for (int j = 0; j < 4; j++)
            acc[i][j] = (fx4){0.f, 0.f, 0.f, 0.f};

    const short* Ab = u + (size_t)b * 256;
    const short* Bb = w1T + (size_t)k * 65536;
    const int srow = lane >> 3;
    const int scol = ((lane & 7) ^ (lane >> 3)) * 8;
    const int fr = lane & 15, g = lane >> 4;
    const int fswz = (fr & 7) << 3;

    for (int k0 = 0; k0 < 256; k0 += 64) {
        __syncthreads();
        {   // A: 128 rows -> 16 gld16 (2/wave); B: 256 rows -> 32 (4/wave)
            const int ra0 = w*16;
            gld16(&As[ra0*64],      &Ab[(size_t)(m0 + ra0 + srow)*1024 + k0 + scol]);
            gld16(&As[(ra0+8)*64],  &Ab[(size_t)(m0 + ra0 + 8 + srow)*1024 + k0 + scol]);
            #pragma unroll
            for (int c = 0; c < 4; c++) {
                const int rb = w*32 + c*8;
                gld16(&Bs[rb*64], &Bb[(size_t)(rb + srow)*256 + k0 + scol]);
            }
        }
        __syncthreads();

        #pragma unroll
        for (int ks = 0; ks < 2; ks++) {
            const int co = (ks*32 + g*8) ^ fswz;
            s16x8 af[4], bfr[4];
            #pragma unroll
            for (int i = 0; i < 4; i++) {
                af[i]  = *(const s16x8*)&As[(wm*64 + i*16 + fr)*64 + co];
                bfr[i] = *(const s16x8*)&Bs[(wn*64 + i*16 + fr)*64 + co];
            }
            #pragma unroll
            for (int i = 0; i < 4; i++)
                #pragma unroll
                for (int j = 0; j < 4; j++)
                    acc[i][j] = __builtin_amdgcn_mfma_f32_16x16x32_bf16(
                                    af[i], bfr[j], acc[i][j], 0, 0, 0);
        }
    }
    __syncthreads();   // all frag reads done before hid overwrites staging

    // phase 2a: gelu + bf16, scatter into hid[128][260]
    const int cr = (lane >> 4) * 4, cc = lane & 15;
    #pragma unroll
    for (int i = 0; i < 4; i++) {
        #pragma unroll
        for (int j = 0; j < 4; j++) {
            const int col = wn*64 + j*16 + cc;
            const float bb = b1s[col];
            #pragma unroll
            for (int r = 0; r < 4; r++) {
                const int row = wm*64 + i*16 + cr + r;
                hid[row*260 + col] = f2bf(gelu_f(acc[i][j][r] + bb));
            }
        }
    }
    __syncthreads();

    // phase 2b: out[row][o] = sum_c hid[row][c] * w2[c][o]  (1 thread each)
    const int koff = (k==0) ? 0 : (k==1) ? 3 : (k==2) ? 4 : (k==3) ? 7 : 11;
    const int kcnt = (k==1) ? 1 : (k==3) ? 4 : 3;
    {
        const int row = t >> 2, o = t & 3;
        float a = 0.f;
        const short* hrow = &hid[row*260];
        #pragma unroll 8
        for (int c4 = 0; c4 < 64; c4++) {
            uint2 hv = *(const uint2*)&hrow[c4*4];
            a += b2f((short)(hv.x & 0xFFFF))       * w2s[(c4*4+0)*4 + o];
            a += b2f((short)(hv.x >> 16))          * w2s[(c4*4+1)*4 + o];
            a += b2f((short)(hv.y & 0xFFFF))       * w2s[(c4*4+2)*4 + o];
            a += b2f((short)(hv.y >> 16))          * w2s[(c4*4+3)*4 + o];
        }
        const int m = m0 + row;
        if (o < kcnt && m < M_)
            outp[((size_t)b*M_ + m)*14 + koff + o] = a + b2[k*4 + o];
    }
}

// ---------------------------------------------------------------------------
extern "C" void kernel_launch(void* const* d_in, const int* in_sizes, int n_in,
                              void* d_out, int out_size, void* d_ws, size_t ws_size,
                              hipStream_t stream)
{
    const float* x          = (const float*)d_in[0];
    const float* pre_emb_w  = (const float*)d_in[1];
    const float* pre_emb_b  = (const float*)d_in[2];
    const float* pre_conv_w = (const float*)d_in[3];
    const float* pre_conv_b = (const float*)d_in[4];
    const float* pos_emb    = (const float*)d_in[5];
    const float* pre_norm_g = (const float*)d_in[6];
    const float* pre_norm_b = (const float*)d_in[7];
    const float* ln1_g      = (const float*)d_in[8];
    const float* ln1_b      = (const float*)d_in[9];
    const float* qkv_w      = (const float*)d_in[10];
    const float* out_w      = (const float*)d_in[11];
    const float* out_b      = (const float*)d_in[12];
    const float* ln2_g      = (const float*)d_in[13];
    const float* ln2_b      = (const float*)d_in[14];
    const float* ff_w1      = (const float*)d_in[15];
    const float* ff_b1      = (const float*)d_in[16];
    const float* ff_w2      = (const float*)d_in[17];
    const float* ff_b2      = (const float*)d_in[18];
    const float* up_w       = (const float*)d_in[19];
    const float* up_b       = (const float*)d_in[20];
    const float* heads_w1   = (const float*)d_in[21];
    const float* heads_b1   = (const float*)d_in[22];
    const float* heads_w2   = (const float*)d_in[23];
    const float* heads_b2   = (const float*)d_in[24];
    float* out = (float*)d_out;

    // ---- workspace layout (bytes) -----------------------------------------
    char* ws = (char*)d_ws;
    float* h      = (float*)(ws);                 //  8,388,608 (fp32 residual)
    char*  R2     = ws + 8388608;
    short* y_bf   = (short*)(R2);                 //  4,194,304
    short* qkv_bf = (short*)(R2 + 4194304);       // 25,165,824
    short* ffmid  = qkv_bf;                       // alias (disjoint lifetime)
    short* obuf   = (short*)(R2 + 29360128);      //  8,388,608
    short* qkvT   = (short*)(R2 + 37748736);      //  3,145,728
    short* outT   = (short*)(R2 + 40894464);      //  1,048,576
    short* ff1T   = (short*)(R2 + 41943040);      //  2,097,152
    short* ff2T   = (short*)(R2 + 44040192);      //  2,097,152
    short* upw_bf = (short*)(R2);                 // aliases R2 post-layers
    short* hT     = (short*)(ws + 65011712);      //  4,194,304 ([1024][2048])
    short* u_bf   = (short*)(ws + 69206016);      // 28,311,552 ([MP][1024])
    short* w1T    = (short*)(ws + 97517568);      //    655,360

    // ---- weight transpose-converts (fp32 [K][N] -> bf16 [N][K]) -----------
    tcvt_kernel<<<dim3(1536/32,  256/32, 4), 256, 0, stream>>>(qkv_w,    qkvT, 256, 1536, 256L*1536, 1536L*256);
    tcvt_kernel<<<dim3( 256/32,  512/32, 4), 256, 0, stream>>>(out_w,    outT, 512,  256, 512L*256,  256L*512);
    tcvt_kernel<<<dim3(1024/32,  256/32, 4), 256, 0, stream>>>(ff_w1,    ff1T, 256, 1024, 256L*1024, 1024L*256);
    tcvt_kernel<<<dim3( 256/32, 1024/32, 4), 256, 0, stream>>>(ff_w2,    ff2T, 1024, 256, 1024L*256, 256L*1024);
    tcvt_kernel<<<dim3( 256/32,  256/32, 5), 256, 0, stream>>>(heads_w1, w1T,  256,  256, 256L*256,  256L*256);

    embed_ln_kernel<<<dim3(N_, B_), 256, 0, stream>>>(
        x, pre_emb_w, pre_emb_b, pre_conv_w, pre_conv_b, pos_emb,
        pre_norm_g, pre_norm_b, h);

    const int rows = B_ * N_;   // 8192
    for (int i = 0; i < L_; i++) {
        ln_bf_kernel<<<rows, 256, 0, stream>>>(h, y_bf, ln1_g + i*D_, ln1_b + i*D_);
        gemm_bf16_kernel<0,0,0,0,1><<<dim3(12, rows/128, 1), 256, 0, stream>>>(
            y_bf, 256, 0, qkvT + (size_t)i*1536*256, 256, 0,
            qkv_bf, 1536, 0, nullptr, 0, rows, 256);
        attn_mfma_kernel<<<dim3(N_/128, H_, B_), 256, 0, stream>>>(qkv_bf, obuf);
        gemm_bf16_kernel<1,0,0,1,0><<<dim3(2, rows/128, 1), 256, 0, stream>>>(
            obuf, 512, 0, outT + (size_t)i*256*512, 512, 0,
            h, 256, 0, out_b + i*D_, 0, rows, 512);
        ln_bf_kernel<<<rows, 256, 0, stream>>>(h, y_bf, ln2_g + i*D_, ln2_b + i*D_);
        gemm_bf16_kernel<1,0,1,0,1><<<dim3(8, rows/128, 1), 256, 0, stream>>>(
            y_bf, 256, 0, ff1T + (size_t)i*1024*256, 256, 0,
            ffmid, 1024, 0, ff_b1 + i*FF_, 0, rows, 256);
        gemm_bf16_kernel<1,0,0,1,0><<<dim3(2, rows/128, 1), 256, 0, stream>>>(
            ffmid, 1024, 0, ff2T + (size_t)i*256*1024, 1024, 0,
            h, 256, 0, ff_b2 + i*D_, 0, rows, 1024);
    }

    // up_w -> bf16
    cvt_kernel<<<13780, 256, 0, stream>>>(up_w, upw_bf);
    // h transpose per batch: [2048,256] -> bf16 [256,2048]; flat = [1024][2048]
    tcvt_kernel<<<dim3(256/32, 2048/32, 4), 256, 0, stream>>>(h, hT, 2048, 256, 2048L*256, 256L*2048);
    // upsample, batches merged into N: u[m][b*256+d], single GEMM N=1024 K=2048
    gemm_bf16_kernel<0,1,0,0,1><<<dim3(8, MP_/128, 1), 256, 0, stream>>>(
        upw_bf, 2048, 0, hT, 2048, 0,
        u_bf, 1024, 0, up_b, 0, M_, 2048);

    // fused gaussian heads v2
    heads_fused_kernel<<<dim3(MP_/128, B_, 5), 512, 0, stream>>>(
        u_bf, w1T, heads_b1, heads_w2, heads_b2, out);
}